// Round 4
// baseline (1062.957 us; speedup 1.0000x reference)
//
#include <hip/hip_runtime.h>
#include <hip/hip_bf16.h>

// ---------------- constants ----------------
#define N_NODES   30000
#define F_IN      768
#define HID       128
#define NHEAD     8
#define C_OUT     4

typedef short short8_t __attribute__((ext_vector_type(8)));
typedef float float4_t __attribute__((ext_vector_type(4)));
typedef int   int4_t   __attribute__((ext_vector_type(4)));

__device__ __forceinline__ float b2f(short u) {
    union { unsigned int i; float f; } v;
    v.i = ((unsigned int)(unsigned short)u) << 16;
    return v.f;
}
__device__ __forceinline__ short f2s(float f) {
    __hip_bfloat16 h = __float2bfloat16(f);
    short s; __builtin_memcpy(&s, &h, 2); return s;
}

// ---------------- workspace layout (bytes) ----------------
#define OFF_H_NEWS      0UL
#define OFF_H_INTER     7680000UL
#define OFF_OUT_NN      15360000UL
#define OFF_OUT_IN      23040000UL
#define OFF_ASRC_NN     30720000UL
#define OFF_ADST_NN     31680000UL
#define OFF_ASRC_IN     32640000UL
#define OFF_ADST_IN     33600000UL
#define OFF_WT_NEWS     34560000UL
#define OFF_WT_INTER    34756608UL
#define OFF_RS_NN       34953216UL
#define OFF_RS_IN       35073280UL
#define OFF_SORT_NN     35193344UL
#define OFF_SORT_IN     37113344UL
#define OFF_ZERO        40953344UL
#define OFF_DEG_NN      40953344UL
#define OFF_FILL_NN     41073408UL
#define OFF_DEG_IN      41193472UL
#define OFF_FILL_IN     41313536UL
#define OFF_SSUM        41433600UL   // 2*128 f32
#define OFF_CNT         41434624UL   // [0]=score done, [1]=count done (16 B zeroed)
#define ZERO_BYTES      481296UL     // OFF_CNT+16 - OFF_ZERO
#define OFF_BETA        41434640UL
#define OFF_FLAG        41434648UL
#define OFF_CPAR        41434656UL
#define OFF_WKT         41470512UL

// canonical param block element offsets
#define CP_B_NEWS  0
#define CP_B_INTER 128
#define CP_ASRC_NN 256
#define CP_ADST_NN 384
#define CP_ASRC_IN 512
#define CP_ADST_IN 640
#define CP_BK      17152
#define CP_Q       17280
#define CP_WOUT    17408
#define CP_BOUT    17920
#define CP_TOTAL   17924

// prep kernel block ranges
#define PREP_CONV_BLOCKS 7
#define PREP_TW_BLOCKS   384
#define PREP_WK_BLOCKS   64
#define PREP_ZERO_BLOCKS 118
#define PREP_B0 PREP_CONV_BLOCKS
#define PREP_B1 (PREP_B0 + 2*PREP_TW_BLOCKS)
#define PREP_B2 (PREP_B1 + PREP_WK_BLOCKS)
#define PREP_TOTAL (PREP_B2 + PREP_ZERO_BLOCKS)

#define GEMM_BX 469            // ceil(30000/64)

// ---------------- fused prep (self-detecting dtype) ----------------
struct SmallParams {
    const void* src[10];
    int n[10];
    int dstoff[10];
};

__global__ void prep(SmallParams sp, short* __restrict__ cp,
                     const void* __restrict__ Wn, const void* __restrict__ Wi,
                     const void* __restrict__ Wkraw,
                     short* __restrict__ WtN, short* __restrict__ WtI,
                     short* __restrict__ wkT,
                     char* __restrict__ zbase,
                     const unsigned int* __restrict__ xprobe,
                     int* __restrict__ flag) {
    __shared__ int cnt_s;
    int b = blockIdx.x, tid = threadIdx.x;
    if (tid == 0) cnt_s = 0;
    __syncthreads();
    int sane = 0;
    for (int i = tid; i < 16384; i += 256) {
        unsigned int lo = xprobe[i] & 0xFFFFu;
        unsigned int ex = (lo >> 7) & 0xFFu;
        if ((ex >= 107u && ex <= 147u) || lo == 0u || lo == 0x8000u) sane++;
    }
    atomicAdd(&cnt_s, sane);
    __syncthreads();
    const bool isbf = (cnt_s > 8192);
    if (b == 0 && tid == 0) *flag = isbf ? 1 : 0;

    if (b < PREP_B0) {
        int idx = b * 256 + tid;
        for (int s = 0; s < 10; ++s) {
            if (idx < sp.n[s]) {
                short v = isbf ? ((const short*)sp.src[s])[idx]
                               : f2s(((const float*)sp.src[s])[idx]);
                cp[sp.dstoff[s] + idx] = v;
                return;
            }
            idx -= sp.n[s];
        }
    } else if (b < PREP_B1) {
        int bb = b - PREP_B0;
        int ty = bb >= PREP_TW_BLOCKS;
        const void* Wraw = ty ? Wi : Wn;
        short* Wt        = ty ? WtI : WtN;
        int idx = (bb - ty * PREP_TW_BLOCKS) * 256 + tid;
        if (idx < F_IN * HID) {
            int n = idx / F_IN;
            int k = idx - n * F_IN;
            Wt[idx] = isbf ? ((const short*)Wraw)[k * HID + n]
                           : f2s(((const float*)Wraw)[k * HID + n]);
        }
    } else if (b < PREP_B2) {
        int idx = (b - PREP_B1) * 256 + tid;
        if (idx < HID * HID) {
            int j = idx >> 7;
            int k = idx & 127;
            wkT[idx] = isbf ? ((const short*)Wkraw)[k * HID + j]
                            : f2s(((const float*)Wkraw)[k * HID + j]);
        }
    } else {
        size_t off = ((size_t)(b - PREP_B2) * 256 + tid) * 16;
        if (off < ZERO_BYTES) *(int4_t*)(zbase + off) = (int4_t){0, 0, 0, 0};
    }
}

// ---------------- projection GEMM: zero-LDS, BM=64, 2-deep register prefetch ----------------
// Wave owns 16 rows. A loads: lanes {quad 0..3} of same lm are 4x16B contiguous -> 64B
// granule-coalesced (verified R2: FETCH stayed ~95MB with this pattern). B is L2-hot.
// 9 x 16B loads in flight per wave (vs 3 in R1) -> 3x MLP.
template<bool ISBF>
__device__ __forceinline__ void gemm_body(
    const void* __restrict__ Xraw, const short* __restrict__ Wt,
    const short* __restrict__ cp, short* __restrict__ Hout,
    float* __restrict__ dot0, float* __restrict__ dot1, float* __restrict__ dot2,
    int ty, int m0, int M)
{
    int tid  = threadIdx.x;
    int lane = tid & 63;
    int wid  = tid >> 6;
    int quad = lane >> 4;
    int lm   = lane & 15;

    int gm_a = m0 + wid * 16 + lm; if (gm_a >= M) gm_a = M - 1;
    const short* as0 = (const short*)Xraw + (size_t)gm_a * F_IN + quad * 8;
    const float* af0 = (const float*)Xraw + (size_t)gm_a * F_IN + quad * 8;
    const short* bb  = Wt + (size_t)lm * F_IN + quad * 8;

    float4_t acc[8];
    #pragma unroll
    for (int c = 0; c < 8; ++c) acc[c] = (float4_t){0.f, 0.f, 0.f, 0.f};

    short8_t bA[8], bB[8];
    short8_t aAs, aBs;
    float4_t aAf0, aAf1, aBf0, aBf1;

#define PC_LOADA(K1) do { \
        if (ISBF) { aAs = *(const short8_t*)(as0 + (K1)); } \
        else { aAf0 = *(const float4_t*)(af0 + (K1)); aAf1 = *(const float4_t*)(af0 + (K1) + 4); } \
        _Pragma("unroll") \
        for (int c = 0; c < 8; ++c) bA[c] = *(const short8_t*)(bb + (size_t)c * 16 * F_IN + (K1)); \
    } while (0)
#define PC_LOADB(K1) do { \
        if (ISBF) { aBs = *(const short8_t*)(as0 + (K1)); } \
        else { aBf0 = *(const float4_t*)(af0 + (K1)); aBf1 = *(const float4_t*)(af0 + (K1) + 4); } \
        _Pragma("unroll") \
        for (int c = 0; c < 8; ++c) bB[c] = *(const short8_t*)(bb + (size_t)c * 16 * F_IN + (K1)); \
    } while (0)
#define PC_STEPA() do { \
        short8_t afr; \
        if (ISBF) afr = aAs; \
        else { _Pragma("unroll") for (int j = 0; j < 4; ++j) { afr[j] = f2s(aAf0[j]); afr[4+j] = f2s(aAf1[j]); } } \
        _Pragma("unroll") \
        for (int c = 0; c < 8; ++c) acc[c] = __builtin_amdgcn_mfma_f32_16x16x32_bf16(afr, bA[c], acc[c], 0, 0, 0); \
    } while (0)
#define PC_STEPB() do { \
        short8_t afr; \
        if (ISBF) afr = aBs; \
        else { _Pragma("unroll") for (int j = 0; j < 4; ++j) { afr[j] = f2s(aBf0[j]); afr[4+j] = f2s(aBf1[j]); } } \
        _Pragma("unroll") \
        for (int c = 0; c < 8; ++c) acc[c] = __builtin_amdgcn_mfma_f32_16x16x32_bf16(afr, bB[c], acc[c], 0, 0, 0); \
    } while (0)

    PC_LOADA(0);
    #pragma unroll
    for (int kc = 0; kc < 24; kc += 2) {
        if (kc + 1 < 24) PC_LOADB((kc + 1) * 32);
        PC_STEPA();
        if (kc + 2 < 24) PC_LOADA((kc + 2) * 32);
        PC_STEPB();
    }
#undef PC_LOADA
#undef PC_LOADB
#undef PC_STEPA
#undef PC_STEPB

    // ---- epilogue: H store + fused head dots ----
    // C/D layout: col = c*16+lm, row = wid*16 + quad*4 + r
    const short* bias = cp + (ty ? CP_B_INTER : CP_B_NEWS);
    const short* aw0  = cp + (ty ? CP_ASRC_IN : CP_ASRC_NN);
    const short* aw1  = cp + CP_ADST_NN;
    const short* aw2  = cp + CP_ADST_IN;

    #pragma unroll
    for (int r = 0; r < 4; ++r) {
        int gm = m0 + wid * 16 + quad * 4 + r;
        bool ok = gm < M;
        float d0a[8], d1a[8], d2a[8];
        #pragma unroll
        for (int c = 0; c < 8; ++c) {
            int col = c * 16 + lm;
            float hval = acc[c][r] + b2f(bias[col]);
            if (ok) Hout[(size_t)gm * HID + col] = f2s(hval);
            float d0 = hval * b2f(aw0[col]);
            float d1 = hval * b2f(aw1[col]);
            float d2 = hval * b2f(aw2[col]);
            #pragma unroll
            for (int off = 1; off < 16; off <<= 1) {
                d0 += __shfl_xor(d0, off, 16);
                if (ty == 0) {
                    d1 += __shfl_xor(d1, off, 16);
                    d2 += __shfl_xor(d2, off, 16);
                }
            }
            d0a[c] = d0; d1a[c] = d1; d2a[c] = d2;
        }
        if (lm == 0 && ok) {
            float4_t v0 = {d0a[0], d0a[1], d0a[2], d0a[3]};
            float4_t v1 = {d0a[4], d0a[5], d0a[6], d0a[7]};
            *(float4_t*)(dot0 + (size_t)gm * NHEAD)     = v0;
            *(float4_t*)(dot0 + (size_t)gm * NHEAD + 4) = v1;
            if (ty == 0) {
                float4_t w0 = {d1a[0], d1a[1], d1a[2], d1a[3]};
                float4_t w1 = {d1a[4], d1a[5], d1a[6], d1a[7]};
                *(float4_t*)(dot1 + (size_t)gm * NHEAD)     = w0;
                *(float4_t*)(dot1 + (size_t)gm * NHEAD + 4) = w1;
                float4_t u0 = {d2a[0], d2a[1], d2a[2], d2a[3]};
                float4_t u1 = {d2a[4], d2a[5], d2a[6], d2a[7]};
                *(float4_t*)(dot2 + (size_t)gm * NHEAD)     = u0;
                *(float4_t*)(dot2 + (size_t)gm * NHEAD + 4) = u1;
            }
        }
    }
}

// count blocks FIRST (so counting+prefix overlap with GEMM), then GEMM blocks.
// Last-finishing count block runs both prefix scans inline (no spin -> deadlock-free).
__global__ __launch_bounds__(256, 4) void proj_count(
    const void* __restrict__ Xn, const void* __restrict__ Xi,
    const short* __restrict__ WtN, const short* __restrict__ WtI,
    const short* __restrict__ cp,
    short* __restrict__ Hn, short* __restrict__ Hi,
    float* __restrict__ asrc_nn, float* __restrict__ adst_nn,
    float* __restrict__ asrc_in, float* __restrict__ adst_in,
    const int* __restrict__ dnn, int Enn,
    const int* __restrict__ din, int Ein,
    int* __restrict__ deg_nn, int* __restrict__ deg_in,
    int* __restrict__ rs_nn, int* __restrict__ rs_in,
    int cntB, int* __restrict__ cnt_done,
    int M, const int* __restrict__ flag)
{
    __shared__ int psum[256];
    __shared__ int lastflag;
    int b = blockIdx.x, tid = threadIdx.x;

    if (b < cntB) {
        int i = b * 256 + tid;
        if (i < Enn) {
            int d = dnn[i];
            if ((unsigned)d < (unsigned)N_NODES) atomicAdd(&deg_nn[d], 1);
        } else {
            int j = i - Enn;
            if (j < Ein) {
                int d = din[j];
                if ((unsigned)d < (unsigned)N_NODES) atomicAdd(&deg_in[d], 1);
            }
        }
        __threadfence();
        __syncthreads();
        if (tid == 0) {
            int old = atomicAdd(cnt_done, 1);
            lastflag = (old == cntB - 1) ? 1 : 0;
        }
        __syncthreads();
        if (!lastflag) return;
        __threadfence();
        for (int pass = 0; pass < 2; ++pass) {
            int* deg = pass ? deg_in : deg_nn;
            int* rsx = pass ? rs_in : rs_nn;
            const int chunk = (N_NODES + 255) / 256;
            int lo = tid * chunk;
            int hi = lo + chunk; if (hi > N_NODES) hi = N_NODES; if (lo > N_NODES) lo = N_NODES;
            int s = 0;
            for (int i2 = lo; i2 < hi; ++i2) s += atomicAdd(&deg[i2], 0);   // coherent read
            psum[tid] = s;
            __syncthreads();
            for (int off = 1; off < 256; off <<= 1) {
                int v = (tid >= off) ? psum[tid - off] : 0;
                __syncthreads();
                psum[tid] += v;
                __syncthreads();
            }
            int base = tid ? psum[tid - 1] : 0;
            for (int i2 = lo; i2 < hi; ++i2) { rsx[i2] = base; base += atomicAdd(&deg[i2], 0); }
            if (tid == 255) rsx[N_NODES] = psum[255];
            __syncthreads();
        }
        return;
    }

    b -= cntB;
    const bool isbf = (*flag != 0);
    int ty = b >= GEMM_BX;
    int bx = b - ty * GEMM_BX;
    int m0 = bx * 64;

    const void* Xraw = ty ? Xi : Xn;
    const short* Wt  = ty ? WtI : WtN;
    short* Hout      = ty ? Hi : Hn;
    float* dot0      = ty ? asrc_in : asrc_nn;

    if (isbf) gemm_body<true >(Xraw, Wt, cp, Hout, dot0, adst_nn, adst_in, ty, m0, M);
    else      gemm_body<false>(Xraw, Wt, cp, Hout, dot0, adst_nn, adst_in, ty, m0, M);
}

// ---------------- edge scatter ----------------
__global__ void scatter_edges2(const int* __restrict__ enn, int Enn,
                               const int* __restrict__ ein, int Ein,
                               const int* __restrict__ rs_nn, int* __restrict__ fill_nn,
                               int* __restrict__ sort_nn,
                               const int* __restrict__ rs_in, int* __restrict__ fill_in,
                               int* __restrict__ sort_in) {
    int i = blockIdx.x * 256 + threadIdx.x;
    if (i < Enn) {
        int d = enn[Enn + i];
        if (d >= 0 && d < N_NODES) {
            int pos = rs_nn[d] + atomicAdd(&fill_nn[d], 1);
            if (pos >= 0 && pos < Enn) sort_nn[pos] = enn[i];
        }
    } else {
        int j = i - Enn;
        if (j < Ein) {
            int d = ein[Ein + j];
            if (d >= 0 && d < N_NODES) {
                int pos = rs_in[d] + atomicAdd(&fill_in[d], 1);
                if (pos >= 0 && pos < Ein) sort_in[pos] = ein[j];
            }
        }
    }
}

// ---------------- fused edge-softmax + aggregation, wave-per-node ----------------
__global__ __launch_bounds__(256) void aggregate2(
    const short* __restrict__ Hnn, const short* __restrict__ Hin,
    const float* __restrict__ asrc_nn, const float* __restrict__ adst_nn,
    const float* __restrict__ asrc_in, const float* __restrict__ adst_in,
    const int* __restrict__ rs_nn, const int* __restrict__ rs_in,
    const int* __restrict__ sort_nn, const int* __restrict__ sort_in,
    short* __restrict__ out_nn, short* __restrict__ out_in)
{
    int tid = threadIdx.x, w = tid >> 6, lane = tid & 63;
    int type = blockIdx.y;
    const short* H    = type ? Hin : Hnn;
    const float* asrc = type ? asrc_in : asrc_nn;
    const float* adst = type ? adst_in : adst_nn;
    const int*   rs   = type ? rs_in : rs_nn;
    const int*   ss   = type ? sort_in : sort_nn;
    short* outb       = type ? out_in : out_nn;

    int dn = blockIdx.x * 4 + w;
    int start = rs[dn], end = rs[dn + 1];
    int head = lane >> 3;
    float adv = adst[dn * NHEAD + head];
    const short* Hl = H + lane * 2;

    float den = 0.f, a0 = 0.f, a1 = 0.f;
    for (int base = start; base < end; base += 64) {
        int nb = end - base; if (nb > 64) nb = 64;
        int myidx = 0;
        if (base + lane < end) {
            int t = ss[base + lane];
            myidx = (t < 0) ? 0 : (t >= N_NODES ? N_NODES - 1 : t);
        }
        int j = 0;
        for (; j + 4 <= nb; j += 4) {
            int s0 = __shfl(myidx, j, 64);
            int s1 = __shfl(myidx, j + 1, 64);
            int s2 = __shfl(myidx, j + 2, 64);
            int s3 = __shfl(myidx, j + 3, 64);
            float v0 = asrc[s0 * NHEAD + head];
            float v1 = asrc[s1 * NHEAD + head];
            float v2 = asrc[s2 * NHEAD + head];
            float v3 = asrc[s3 * NHEAD + head];
            unsigned int q0 = *(const unsigned int*)(Hl + (size_t)s0 * HID);
            unsigned int q1 = *(const unsigned int*)(Hl + (size_t)s1 * HID);
            unsigned int q2 = *(const unsigned int*)(Hl + (size_t)s2 * HID);
            unsigned int q3 = *(const unsigned int*)(Hl + (size_t)s3 * HID);
            float e0 = v0 + adv, e1 = v1 + adv, e2 = v2 + adv, e3 = v3 + adv;
            e0 = fmaxf(e0, 0.2f * e0); e1 = fmaxf(e1, 0.2f * e1);
            e2 = fmaxf(e2, 0.2f * e2); e3 = fmaxf(e3, 0.2f * e3);
            e0 = fminf(e0, 80.f); e1 = fminf(e1, 80.f);
            e2 = fminf(e2, 80.f); e3 = fminf(e3, 80.f);
            float x0 = __expf(e0), x1 = __expf(e1), x2 = __expf(e2), x3 = __expf(e3);
            union { unsigned int u; float f; } cl0, ch0, cl1, ch1, cl2, ch2, cl3, ch3;
            cl0.u = q0 << 16; ch0.u = q0 & 0xFFFF0000u;
            cl1.u = q1 << 16; ch1.u = q1 & 0xFFFF0000u;
            cl2.u = q2 << 16; ch2.u = q2 & 0xFFFF0000u;
            cl3.u = q3 << 16; ch3.u = q3 & 0xFFFF0000u;
            den += x0; den += x1; den += x2; den += x3;
            a0 = fmaf(x0, cl0.f, a0); a0 = fmaf(x1, cl1.f, a0);
            a0 = fmaf(x2, cl2.f, a0); a0 = fmaf(x3, cl3.f, a0);
            a1 = fmaf(x0, ch0.f, a1); a1 = fmaf(x1, ch1.f, a1);
            a1 = fmaf(x2, ch2.f, a1); a1 = fmaf(x3, ch3.f, a1);
        }
        for (; j < nb; ++j) {
            int s0 = __shfl(myidx, j, 64);
            float v0 = asrc[s0 * NHEAD + head];
            unsigned int q0 = *(const unsigned int*)(Hl + (size_t)s0 * HID);
            float e0 = v0 + adv;
            e0 = fmaxf(e0, 0.2f * e0);
            e0 = fminf(e0, 80.f);
            float x0 = __expf(e0);
            union { unsigned int u; float f; } cl0, ch0;
            cl0.u = q0 << 16; ch0.u = q0 & 0xFFFF0000u;
            den += x0;
            a0 = fmaf(x0, cl0.f, a0);
            a1 = fmaf(x0, ch0.f, a1);
        }
    }
    float inv = 1.f / (den + 1e-16f);
    unsigned int lo16 = (unsigned short)f2s(fmaxf(a0 * inv, 0.f));
    unsigned int hi16 = (unsigned short)f2s(fmaxf(a1 * inv, 0.f));
    *(unsigned int*)(outb + (size_t)dn * HID + lane * 2) = lo16 | (hi16 << 16);
}

// ---------------- semantic score via MFMA (+fused beta in last block) ----------------
__global__ __launch_bounds__(256) void score_mfma(
    const short* __restrict__ out_nn, const short* __restrict__ out_in,
    const short* __restrict__ wkT, const short* __restrict__ cp,
    float* __restrict__ Ssum, int* __restrict__ done_cnt,
    float* __restrict__ beta, int total_blocks)
{
    __shared__ float col_s[HID];
    __shared__ int lastflag;
    int tid  = threadIdx.x;
    int lane = tid & 63;
    int wid  = tid >> 6;
    int quad = lane >> 4;
    int lm   = lane & 15;
    const short* src = blockIdx.y ? out_in : out_nn;
    int m0 = blockIdx.x * 128;

    if (tid < HID) col_s[tid] = 0.f;
    __syncthreads();

    float4_t acc[2][8];
    #pragma unroll
    for (int i = 0; i < 2; ++i)
        #pragma unroll
        for (int c = 0; c < 8; ++c)
            acc[i][c] = (float4_t){0.f, 0.f, 0.f, 0.f};

    #pragma unroll
    for (int kc = 0; kc < 4; ++kc) {
        short8_t bfrag[8];
        #pragma unroll
        for (int c = 0; c < 8; ++c)
            bfrag[c] = *(const short8_t*)(wkT + (c * 16 + lm) * HID + kc * 32 + quad * 8);
        #pragma unroll
        for (int i = 0; i < 2; ++i) {
            int gm = m0 + wid * 32 + i * 16 + lm;
            if (gm >= N_NODES) gm = N_NODES - 1;
            short8_t afrag = *(const short8_t*)(src + (size_t)gm * HID + kc * 32 + quad * 8);
            #pragma unroll
            for (int c = 0; c < 8; ++c)
                acc[i][c] = __builtin_amdgcn_mfma_f32_16x16x32_bf16(afrag, bfrag[c], acc[i][c], 0, 0, 0);
        }
    }

    #pragma unroll
    for (int c = 0; c < 8; ++c) {
        int col = c * 16 + lm;
        float bkc = b2f(cp[CP_BK + col]);
        float lsum = 0.f;
        #pragma unroll
        for (int i = 0; i < 2; ++i)
            #pragma unroll
            for (int r = 0; r < 4; ++r) {
                int node = m0 + wid * 32 + i * 16 + quad * 4 + r;
                if (node < N_NODES) {
                    float a = acc[i][c][r] + bkc;
                    a = fminf(fmaxf(a, -15.f), 15.f);
                    float t = __expf(2.f * a);
                    lsum += (t - 1.f) / (t + 1.f);
                }
            }
        float v = lsum;
        v += __shfl_down(v, 32, 64);
        v += __shfl_down(v, 16, 64);
        if (quad == 0) atomicAdd(&col_s[col], v);
    }
    __syncthreads();
    if (tid < HID) atomicAdd(&Ssum[blockIdx.y * HID + tid], col_s[tid]);
    __syncthreads();

    if (tid == 0) {
        __threadfence();
        int old = atomicAdd(done_cnt, 1);
        lastflag = (old == total_blocks - 1) ? 1 : 0;
    }
    __syncthreads();
    if (lastflag && tid < 64) {
        float s00 = atomicAdd(&Ssum[tid], 0.f);
        float s01 = atomicAdd(&Ssum[tid + 64], 0.f);
        float s10 = atomicAdd(&Ssum[128 + tid], 0.f);
        float s11 = atomicAdd(&Ssum[192 + tid], 0.f);
        float q0 = b2f(cp[CP_Q + tid]), q1 = b2f(cp[CP_Q + tid + 64]);
        float v0 = q0 * s00 + q1 * s01;
        float v1 = q0 * s10 + q1 * s11;
        #pragma unroll
        for (int off = 32; off; off >>= 1) {
            v0 += __shfl_down(v0, off, 64);
            v1 += __shfl_down(v1, off, 64);
        }
        if (tid == 0) {
            float sc0 = v0 / (float)N_NODES;
            float sc1 = v1 / (float)N_NODES;
            float mx = fmaxf(sc0, sc1);
            float e0 = __expf(sc0 - mx), e1 = __expf(sc1 - mx);
            float inv = 1.f / (e0 + e1);
            beta[0] = e0 * inv;
            beta[1] = e1 * inv;
        }
    }
}

// ---------------- final ----------------
__global__ __launch_bounds__(256) void final_out(
    const short* __restrict__ out_nn, const short* __restrict__ out_in,
    const float* __restrict__ beta, const short* __restrict__ cp,
    void* __restrict__ Yraw, const int* __restrict__ flag)
{
    bool isbf = (*flag != 0);
    int tid = threadIdx.x, lane = tid & 63, w = tid >> 6;
    int n = blockIdx.x * 4 + w;
    float b0 = beta[0], b1 = beta[1];
    unsigned int u0 = *(const unsigned int*)(out_nn + (size_t)n * HID + lane * 2);
    unsigned int u1 = *(const unsigned int*)(out_in + (size_t)n * HID + lane * 2);
    union { unsigned int u; float f; } t;
    t.u = u0 << 16;          float f0 = b0 * t.f;
    t.u = u0 & 0xFFFF0000u;  float f1 = b0 * t.f;
    t.u = u1 << 16;          f0 += b1 * t.f;
    t.u = u1 & 0xFFFF0000u;  f1 += b1 * t.f;
    float e0 = (f0 > 0.f) ? f0 : expm1f(f0);
    float e1 = (f1 > 0.f) ? f1 : expm1f(f1);
    int c0 = lane * 2, c1 = lane * 2 + 1;
    float p[C_OUT];
    #pragma unroll
    for (int c = 0; c < C_OUT; ++c)
        p[c] = e0 * b2f(cp[CP_WOUT + c0 * C_OUT + c]) + e1 * b2f(cp[CP_WOUT + c1 * C_OUT + c]);
    #pragma unroll
    for (int off = 32; off; off >>= 1)
        #pragma unroll
        for (int c = 0; c < C_OUT; ++c) p[c] += __shfl_down(p[c], off, 64);
    if (lane == 0) {
        #pragma unroll
        for (int c = 0; c < C_OUT; ++c) {
            float r = p[c] + b2f(cp[CP_BOUT + c]);
            if (isbf) ((__hip_bfloat16*)Yraw)[n * C_OUT + c] = __float2bfloat16(r);
            else      ((float*)Yraw)[n * C_OUT + c] = r;
        }
    }
}

// ---------------- launch ----------------
extern "C" void kernel_launch(void* const* d_in, const int* in_sizes, int n_in,
                              void* d_out, int out_size, void* d_ws, size_t ws_size,
                              hipStream_t stream) {
    const void* x_news  = d_in[0];
    const void* x_inter = d_in[1];
    const int*  edge_nn = (const int*)d_in[2];
    const int*  edge_in = (const int*)d_in[3];

    int E_nn = in_sizes[2] / 2;
    int E_in = in_sizes[3] / 2;

    char* ws = (char*)d_ws;
    short* h_news  = (short*)(ws + OFF_H_NEWS);
    short* h_inter = (short*)(ws + OFF_H_INTER);
    short* out_nn  = (short*)(ws + OFF_OUT_NN);
    short* out_in  = (short*)(ws + OFF_OUT_IN);
    float* asrc_nn = (float*)(ws + OFF_ASRC_NN);
    float* adst_nn = (float*)(ws + OFF_ADST_NN);
    float* asrc_in = (float*)(ws + OFF_ASRC_IN);
    float* adst_in = (float*)(ws + OFF_ADST_IN);
    short* wt_news  = (short*)(ws + OFF_WT_NEWS);
    short* wt_inter = (short*)(ws + OFF_WT_INTER);
    int* rs_nn   = (int*)(ws + OFF_RS_NN);
    int* rs_in   = (int*)(ws + OFF_RS_IN);
    int* sort_nn = (int*)(ws + OFF_SORT_NN);
    int* sort_in = (int*)(ws + OFF_SORT_IN);
    int* deg_nn  = (int*)(ws + OFF_DEG_NN);
    int* fill_nn = (int*)(ws + OFF_FILL_NN);
    int* deg_in  = (int*)(ws + OFF_DEG_IN);
    int* fill_in = (int*)(ws + OFF_FILL_IN);
    float* Ssum  = (float*)(ws + OFF_SSUM);
    int*   dcnt  = (int*)(ws + OFF_CNT);
    float* beta  = (float*)(ws + OFF_BETA);
    int*   flag  = (int*)(ws + OFF_FLAG);
    short* cp    = (short*)(ws + OFF_CPAR);
    short* wkT   = (short*)(ws + OFF_WKT);

    SmallParams sp;
    const int srcidx[10] = {5, 7, 8, 9, 10, 11, 13, 14, 15, 16};
    const int ns[10]     = {128, 128, 128, 128, 128, 128, 128, 128, 512, 4};
    const int doff[10]   = {CP_B_NEWS, CP_B_INTER, CP_ASRC_NN, CP_ADST_NN, CP_ASRC_IN,
                            CP_ADST_IN, CP_BK, CP_Q, CP_WOUT, CP_BOUT};
    for (int i = 0; i < 10; ++i) { sp.src[i] = d_in[srcidx[i]]; sp.n[i] = ns[i]; sp.dstoff[i] = doff[i]; }

    prep<<<PREP_TOTAL, 256, 0, stream>>>(sp, cp, d_in[4], d_in[6], d_in[12],
                                         wt_news, wt_inter, wkT, ws + OFF_ZERO,
                                         (const unsigned int*)x_news, flag);

    int cntB = (E_nn + E_in + 255) / 256;
    proj_count<<<cntB + 2 * GEMM_BX, 256, 0, stream>>>(
        x_news, x_inter, wt_news, wt_inter, cp, h_news, h_inter,
        asrc_nn, adst_nn, asrc_in, adst_in,
        edge_nn + E_nn, E_nn, edge_in + E_in, E_in,
        deg_nn, deg_in, rs_nn, rs_in,
        cntB, dcnt + 1,
        N_NODES, flag);

    scatter_edges2<<<cntB, 256, 0, stream>>>(
        edge_nn, E_nn, edge_in, E_in, rs_nn, fill_nn, sort_nn, rs_in, fill_in, sort_in);

    aggregate2<<<dim3(N_NODES / 4, 2), 256, 0, stream>>>(
        h_news, h_inter, asrc_nn, adst_nn, asrc_in, adst_in,
        rs_nn, rs_in, sort_nn, sort_in, out_nn, out_in);

    int score_bx = (N_NODES + 127) / 128;
    score_mfma<<<dim3(score_bx, 2), 256, 0, stream>>>(
        out_nn, out_in, wkT, cp, Ssum, dcnt, beta, 2 * score_bx);

    final_out<<<N_NODES / 4, 256, 0, stream>>>(out_nn, out_in, beta, cp, d_out, flag);
}

// Round 5
// 1019.058 us; speedup vs baseline: 1.0431x; 1.0431x over previous
//
#include <hip/hip_runtime.h>
#include <hip/hip_bf16.h>

// ---------------- constants ----------------
#define N_NODES   30000
#define F_IN      768
#define HID       128
#define NHEAD     8
#define C_OUT     4

typedef short short8_t __attribute__((ext_vector_type(8)));
typedef float float4_t __attribute__((ext_vector_type(4)));
typedef int   int4_t   __attribute__((ext_vector_type(4)));

__device__ __forceinline__ float b2f(short u) {
    union { unsigned int i; float f; } v;
    v.i = ((unsigned int)(unsigned short)u) << 16;
    return v.f;
}
__device__ __forceinline__ short f2s(float f) {
    __hip_bfloat16 h = __float2bfloat16(f);
    short s; __builtin_memcpy(&s, &h, 2); return s;
}

// async 16B global->LDS (direct DMA; LDS dest = wave-uniform base + lane*16)
__device__ __forceinline__ void gload16(const void* g, void* l) {
    __builtin_amdgcn_global_load_lds(
        (const __attribute__((address_space(1))) void*)g,
        (__attribute__((address_space(3))) void*)l, 16, 0, 0);
}

// ---------------- workspace layout (bytes) ----------------
#define OFF_H_NEWS      0UL
#define OFF_H_INTER     7680000UL
#define OFF_OUT_NN      15360000UL
#define OFF_OUT_IN      23040000UL
#define OFF_ASRC_NN     30720000UL
#define OFF_ADST_NN     31680000UL
#define OFF_ASRC_IN     32640000UL
#define OFF_ADST_IN     33600000UL
#define OFF_WT_NEWS     34560000UL
#define OFF_WT_INTER    34756608UL
#define OFF_RS_NN       34953216UL
#define OFF_RS_IN       35073280UL
#define OFF_SORT_NN     35193344UL
#define OFF_SORT_IN     37113344UL
#define OFF_ZERO        40953344UL
#define OFF_DEG_NN      40953344UL
#define OFF_FILL_NN     41073408UL
#define OFF_DEG_IN      41193472UL
#define OFF_FILL_IN     41313536UL
#define OFF_SSUM        41433600UL   // 2*128 f32
#define OFF_CNT         41434624UL   // [0]=score done, [1]=count done (16 B zeroed)
#define ZERO_BYTES      481296UL     // OFF_CNT+16 - OFF_ZERO
#define OFF_BETA        41434640UL
#define OFF_FLAG        41434648UL
#define OFF_CPAR        41434656UL
#define OFF_WKT         41470512UL

// canonical param block element offsets
#define CP_B_NEWS  0
#define CP_B_INTER 128
#define CP_ASRC_NN 256
#define CP_ADST_NN 384
#define CP_ASRC_IN 512
#define CP_ADST_IN 640
#define CP_BK      17152
#define CP_Q       17280
#define CP_WOUT    17408
#define CP_BOUT    17920
#define CP_TOTAL   17924

// prep kernel block ranges
#define PREP_CONV_BLOCKS 7
#define PREP_TW_BLOCKS   384
#define PREP_WK_BLOCKS   64
#define PREP_ZERO_BLOCKS 118
#define PREP_B0 PREP_CONV_BLOCKS
#define PREP_B1 (PREP_B0 + 2*PREP_TW_BLOCKS)
#define PREP_B2 (PREP_B1 + PREP_WK_BLOCKS)
#define PREP_TOTAL (PREP_B2 + PREP_ZERO_BLOCKS)

#define GEMM_BX 469            // ceil(30000/64)
#define BK2     64             // K-chunk
// LDS: As[64][64] + Bs[128][64] shorts, linear (XOR-swizzled content)
#define AS_SHORTS 4096
#define BS_SHORTS 8192

// ---------------- fused prep (self-detecting dtype) ----------------
struct SmallParams {
    const void* src[10];
    int n[10];
    int dstoff[10];
};

__global__ void prep(SmallParams sp, short* __restrict__ cp,
                     const void* __restrict__ Wn, const void* __restrict__ Wi,
                     const void* __restrict__ Wkraw,
                     short* __restrict__ WtN, short* __restrict__ WtI,
                     short* __restrict__ wkT,
                     char* __restrict__ zbase,
                     const unsigned int* __restrict__ xprobe,
                     int* __restrict__ flag) {
    __shared__ int cnt_s;
    int b = blockIdx.x, tid = threadIdx.x;
    if (tid == 0) cnt_s = 0;
    __syncthreads();
    int sane = 0;
    for (int i = tid; i < 16384; i += 256) {
        unsigned int lo = xprobe[i] & 0xFFFFu;
        unsigned int ex = (lo >> 7) & 0xFFu;
        if ((ex >= 107u && ex <= 147u) || lo == 0u || lo == 0x8000u) sane++;
    }
    atomicAdd(&cnt_s, sane);
    __syncthreads();
    const bool isbf = (cnt_s > 8192);
    if (b == 0 && tid == 0) *flag = isbf ? 1 : 0;

    if (b < PREP_B0) {
        int idx = b * 256 + tid;
        for (int s = 0; s < 10; ++s) {
            if (idx < sp.n[s]) {
                short v = isbf ? ((const short*)sp.src[s])[idx]
                               : f2s(((const float*)sp.src[s])[idx]);
                cp[sp.dstoff[s] + idx] = v;
                return;
            }
            idx -= sp.n[s];
        }
    } else if (b < PREP_B1) {
        int bb = b - PREP_B0;
        int ty = bb >= PREP_TW_BLOCKS;
        const void* Wraw = ty ? Wi : Wn;
        short* Wt        = ty ? WtI : WtN;
        int idx = (bb - ty * PREP_TW_BLOCKS) * 256 + tid;
        if (idx < F_IN * HID) {
            int n = idx / F_IN;
            int k = idx - n * F_IN;
            Wt[idx] = isbf ? ((const short*)Wraw)[k * HID + n]
                           : f2s(((const float*)Wraw)[k * HID + n]);
        }
    } else if (b < PREP_B2) {
        int idx = (b - PREP_B1) * 256 + tid;
        if (idx < HID * HID) {
            int j = idx >> 7;
            int k = idx & 127;
            wkT[idx] = isbf ? ((const short*)Wkraw)[k * HID + j]
                            : f2s(((const float*)Wkraw)[k * HID + j]);
        }
    } else {
        size_t off = ((size_t)(b - PREP_B2) * 256 + tid) * 16;
        if (off < ZERO_BYTES) *(int4_t*)(zbase + off) = (int4_t){0, 0, 0, 0};
    }
}

// ---------------- projection GEMM: BK=64, global_load_lds staging, XOR-swizzled LDS ----------------
// LDS content rule: slot(row, j) holds global 16B-chunk k8 = j ^ (row&7).
// Write: per-lane pre-swizzled global source + linear LDS dest (rule #21).
// Read : byte = row*128 + ((k8)^(row&7))*16  -> 8 distinct 16B slots per wave read (all 32 banks).
template<bool ISBF>
__device__ __forceinline__ void gemm_body(
    const void* __restrict__ Xraw, const short* __restrict__ Wt,
    const short* __restrict__ cp, short* __restrict__ Hout,
    float* __restrict__ dot0, float* __restrict__ dot1, float* __restrict__ dot2,
    int ty, int m0, int M, short* __restrict__ SB)
{
    int tid  = threadIdx.x;
    int lane = tid & 63;
    int wid  = tid >> 6;
    int quad = lane >> 4;
    int lm   = lane & 15;

    // ---- staging source pointers (fixed per lane; advance by BK2 per iter) ----
    // A tile (bf16 path): 8 regions of 1KB, m = wid*2+t
    const short* pAs[2];
    short*       lA[2];
    // A tile (fp32 path): thread slots s = tid*2+u
    const float* pAf[2];
    short*       lAf[2];
    if (ISBF) {
        #pragma unroll
        for (int t = 0; t < 2; ++t) {
            int m = wid * 2 + t;
            int s = m * 64 + lane;
            int row = s >> 3, j = s & 7;
            int k8 = j ^ (row & 7);
            int gmr = m0 + row; if (gmr >= M) gmr = M - 1;
            pAs[t] = (const short*)Xraw + (size_t)gmr * F_IN + k8 * 8;
            lA[t]  = SB + m * 512;                    // 1KB region (shorts)
        }
    } else {
        #pragma unroll
        for (int u = 0; u < 2; ++u) {
            int s = tid * 2 + u;
            int row = s >> 3, j = s & 7;
            int k8 = j ^ (row & 7);
            int gmr = m0 + row; if (gmr >= M) gmr = M - 1;
            pAf[u] = (const float*)Xraw + (size_t)gmr * F_IN + k8 * 8;
            lAf[u] = SB + s * 8;                      // 16B slot
        }
    }
    // B tile: 16 regions of 1KB, m = wid*4+t  (B is always bf16)
    const short* pB[4];
    short*       lB[4];
    #pragma unroll
    for (int t = 0; t < 4; ++t) {
        int m = wid * 4 + t;
        int s = m * 64 + lane;
        int row = s >> 3, j = s & 7;
        int k8 = j ^ (row & 7);
        pB[t] = Wt + (size_t)row * F_IN + k8 * 8;
        lB[t] = SB + AS_SHORTS + m * 512;
    }

    // ---- read offsets (loop-invariant; shorts) ----
    int rowa = wid * 16 + lm;
    int aoff[2], boff[2][8];
    #pragma unroll
    for (int kk = 0; kk < 2; ++kk) {
        int k8 = kk * 4 + quad;
        aoff[kk] = rowa * 64 + ((k8 ^ (rowa & 7)) * 8);
        #pragma unroll
        for (int c = 0; c < 8; ++c) {
            int rowb = c * 16 + lm;
            boff[kk][c] = AS_SHORTS + rowb * 64 + ((k8 ^ (rowb & 7)) * 8);
        }
    }

    float4_t acc[8];
    #pragma unroll
    for (int c = 0; c < 8; ++c) acc[c] = (float4_t){0.f, 0.f, 0.f, 0.f};

    for (int it = 0; it < F_IN / BK2; ++it) {
        __syncthreads();                 // prior reads of SB complete
        if (ISBF) {
            #pragma unroll
            for (int t = 0; t < 2; ++t) { gload16(pAs[t], lA[t]); pAs[t] += BK2; }
        } else {
            #pragma unroll
            for (int u = 0; u < 2; ++u) {
                float4_t f0 = *(const float4_t*)pAf[u];
                float4_t f1 = *(const float4_t*)(pAf[u] + 4);
                pAf[u] += BK2;
                short8_t v;
                #pragma unroll
                for (int j = 0; j < 4; ++j) { v[j] = f2s(f0[j]); v[4 + j] = f2s(f1[j]); }
                *(short8_t*)lAf[u] = v;
            }
        }
        #pragma unroll
        for (int t = 0; t < 4; ++t) { gload16(pB[t], lB[t]); pB[t] += BK2; }
        __syncthreads();                 // vmcnt+lgkm drained by compiler before barrier

        #pragma unroll
        for (int kk = 0; kk < 2; ++kk) {
            short8_t bfrag[8];
            #pragma unroll
            for (int c = 0; c < 8; ++c)
                bfrag[c] = *(const short8_t*)(SB + boff[kk][c]);
            short8_t afrag = *(const short8_t*)(SB + aoff[kk]);
            #pragma unroll
            for (int c = 0; c < 8; ++c)
                acc[c] = __builtin_amdgcn_mfma_f32_16x16x32_bf16(afrag, bfrag[c], acc[c], 0, 0, 0);
        }
    }

    // ---- epilogue: H store + fused head dots (verified R1/R4 numerics) ----
    // C/D layout: col = c*16+lm, row = wid*16 + quad*4 + r
    const short* bias = cp + (ty ? CP_B_INTER : CP_B_NEWS);
    const short* aw0  = cp + (ty ? CP_ASRC_IN : CP_ASRC_NN);
    const short* aw1  = cp + CP_ADST_NN;
    const short* aw2  = cp + CP_ADST_IN;

    #pragma unroll
    for (int r = 0; r < 4; ++r) {
        int gm = m0 + wid * 16 + quad * 4 + r;
        bool ok = gm < M;
        float d0a[8], d1a[8], d2a[8];
        #pragma unroll
        for (int c = 0; c < 8; ++c) {
            int col = c * 16 + lm;
            float hval = acc[c][r] + b2f(bias[col]);
            if (ok) Hout[(size_t)gm * HID + col] = f2s(hval);
            float d0 = hval * b2f(aw0[col]);
            float d1 = hval * b2f(aw1[col]);
            float d2 = hval * b2f(aw2[col]);
            #pragma unroll
            for (int off = 1; off < 16; off <<= 1) {
                d0 += __shfl_xor(d0, off, 16);
                if (ty == 0) {
                    d1 += __shfl_xor(d1, off, 16);
                    d2 += __shfl_xor(d2, off, 16);
                }
            }
            d0a[c] = d0; d1a[c] = d1; d2a[c] = d2;
        }
        if (lm == 0 && ok) {
            float4_t v0 = {d0a[0], d0a[1], d0a[2], d0a[3]};
            float4_t v1 = {d0a[4], d0a[5], d0a[6], d0a[7]};
            *(float4_t*)(dot0 + (size_t)gm * NHEAD)     = v0;
            *(float4_t*)(dot0 + (size_t)gm * NHEAD + 4) = v1;
            if (ty == 0) {
                float4_t w0 = {d1a[0], d1a[1], d1a[2], d1a[3]};
                float4_t w1 = {d1a[4], d1a[5], d1a[6], d1a[7]};
                *(float4_t*)(dot1 + (size_t)gm * NHEAD)     = w0;
                *(float4_t*)(dot1 + (size_t)gm * NHEAD + 4) = w1;
                float4_t u0 = {d2a[0], d2a[1], d2a[2], d2a[3]};
                float4_t u1 = {d2a[4], d2a[5], d2a[6], d2a[7]};
                *(float4_t*)(dot2 + (size_t)gm * NHEAD)     = u0;
                *(float4_t*)(dot2 + (size_t)gm * NHEAD + 4) = u1;
            }
        }
    }
}

// count blocks FIRST (counting+prefix overlap with GEMM); last count block does prefix inline.
__global__ __launch_bounds__(256, 4) void proj_count(
    const void* __restrict__ Xn, const void* __restrict__ Xi,
    const short* __restrict__ WtN, const short* __restrict__ WtI,
    const short* __restrict__ cp,
    short* __restrict__ Hn, short* __restrict__ Hi,
    float* __restrict__ asrc_nn, float* __restrict__ adst_nn,
    float* __restrict__ asrc_in, float* __restrict__ adst_in,
    const int* __restrict__ dnn, int Enn,
    const int* __restrict__ din, int Ein,
    int* __restrict__ deg_nn, int* __restrict__ deg_in,
    int* __restrict__ rs_nn, int* __restrict__ rs_in,
    int cntB, int* __restrict__ cnt_done,
    int M, const int* __restrict__ flag)
{
    __shared__ __align__(16) short SB[AS_SHORTS + BS_SHORTS];   // 24576 B
    __shared__ int psum[256];
    __shared__ int lastflag;
    int b = blockIdx.x, tid = threadIdx.x;

    if (b < cntB) {
        int i = b * 256 + tid;
        if (i < Enn) {
            int d = dnn[i];
            if ((unsigned)d < (unsigned)N_NODES) atomicAdd(&deg_nn[d], 1);
        } else {
            int j = i - Enn;
            if (j < Ein) {
                int d = din[j];
                if ((unsigned)d < (unsigned)N_NODES) atomicAdd(&deg_in[d], 1);
            }
        }
        __threadfence();
        __syncthreads();
        if (tid == 0) {
            int old = atomicAdd(cnt_done, 1);
            lastflag = (old == cntB - 1) ? 1 : 0;
        }
        __syncthreads();
        if (!lastflag) return;
        __threadfence();
        for (int pass = 0; pass < 2; ++pass) {
            int* deg = pass ? deg_in : deg_nn;
            int* rsx = pass ? rs_in : rs_nn;
            const int chunk = (N_NODES + 255) / 256;
            int lo = tid * chunk;
            int hi = lo + chunk; if (hi > N_NODES) hi = N_NODES; if (lo > N_NODES) lo = N_NODES;
            int s = 0;
            for (int i2 = lo; i2 < hi; ++i2) s += atomicAdd(&deg[i2], 0);
            psum[tid] = s;
            __syncthreads();
            for (int off = 1; off < 256; off <<= 1) {
                int v = (tid >= off) ? psum[tid - off] : 0;
                __syncthreads();
                psum[tid] += v;
                __syncthreads();
            }
            int base = tid ? psum[tid - 1] : 0;
            for (int i2 = lo; i2 < hi; ++i2) { rsx[i2] = base; base += atomicAdd(&deg[i2], 0); }
            if (tid == 255) rsx[N_NODES] = psum[255];
            __syncthreads();
        }
        return;
    }

    b -= cntB;
    const bool isbf = (*flag != 0);
    int ty = b >= GEMM_BX;
    int bx = b - ty * GEMM_BX;
    int m0 = bx * 64;

    const void* Xraw = ty ? Xi : Xn;
    const short* Wt  = ty ? WtI : WtN;
    short* Hout      = ty ? Hi : Hn;
    float* dot0      = ty ? asrc_in : asrc_nn;

    if (isbf) gemm_body<true >(Xraw, Wt, cp, Hout, dot0, adst_nn, adst_in, ty, m0, M, SB);
    else      gemm_body<false>(Xraw, Wt, cp, Hout, dot0, adst_nn, adst_in, ty, m0, M, SB);
}

// ---------------- edge scatter ----------------
__global__ void scatter_edges2(const int* __restrict__ enn, int Enn,
                               const int* __restrict__ ein, int Ein,
                               const int* __restrict__ rs_nn, int* __restrict__ fill_nn,
                               int* __restrict__ sort_nn,
                               const int* __restrict__ rs_in, int* __restrict__ fill_in,
                               int* __restrict__ sort_in) {
    int i = blockIdx.x * 256 + threadIdx.x;
    if (i < Enn) {
        int d = enn[Enn + i];
        if (d >= 0 && d < N_NODES) {
            int pos = rs_nn[d] + atomicAdd(&fill_nn[d], 1);
            if (pos >= 0 && pos < Enn) sort_nn[pos] = enn[i];
        }
    } else {
        int j = i - Enn;
        if (j < Ein) {
            int d = ein[Ein + j];
            if (d >= 0 && d < N_NODES) {
                int pos = rs_in[d] + atomicAdd(&fill_in[d], 1);
                if (pos >= 0 && pos < Ein) sort_in[pos] = ein[j];
            }
        }
    }
}

// ---------------- fused edge-softmax + aggregation, wave-per-node ----------------
__global__ __launch_bounds__(256) void aggregate2(
    const short* __restrict__ Hnn, const short* __restrict__ Hin,
    const float* __restrict__ asrc_nn, const float* __restrict__ adst_nn,
    const float* __restrict__ asrc_in, const float* __restrict__ adst_in,
    const int* __restrict__ rs_nn, const int* __restrict__ rs_in,
    const int* __restrict__ sort_nn, const int* __restrict__ sort_in,
    short* __restrict__ out_nn, short* __restrict__ out_in)
{
    int tid = threadIdx.x, w = tid >> 6, lane = tid & 63;
    int type = blockIdx.y;
    const short* H    = type ? Hin : Hnn;
    const float* asrc = type ? asrc_in : asrc_nn;
    const float* adst = type ? adst_in : adst_nn;
    const int*   rs   = type ? rs_in : rs_nn;
    const int*   ss   = type ? sort_in : sort_nn;
    short* outb       = type ? out_in : out_nn;

    int dn = blockIdx.x * 4 + w;
    int start = rs[dn], end = rs[dn + 1];
    int head = lane >> 3;
    float adv = adst[dn * NHEAD + head];
    const short* Hl = H + lane * 2;

    float den = 0.f, a0 = 0.f, a1 = 0.f;
    for (int base = start; base < end; base += 64) {
        int nb = end - base; if (nb > 64) nb = 64;
        int myidx = 0;
        if (base + lane < end) {
            int t = ss[base + lane];
            myidx = (t < 0) ? 0 : (t >= N_NODES ? N_NODES - 1 : t);
        }
        int j = 0;
        for (; j + 4 <= nb; j += 4) {
            int s0 = __shfl(myidx, j, 64);
            int s1 = __shfl(myidx, j + 1, 64);
            int s2 = __shfl(myidx, j + 2, 64);
            int s3 = __shfl(myidx, j + 3, 64);
            float v0 = asrc[s0 * NHEAD + head];
            float v1 = asrc[s1 * NHEAD + head];
            float v2 = asrc[s2 * NHEAD + head];
            float v3 = asrc[s3 * NHEAD + head];
            unsigned int q0 = *(const unsigned int*)(Hl + (size_t)s0 * HID);
            unsigned int q1 = *(const unsigned int*)(Hl + (size_t)s1 * HID);
            unsigned int q2 = *(const unsigned int*)(Hl + (size_t)s2 * HID);
            unsigned int q3 = *(const unsigned int*)(Hl + (size_t)s3 * HID);
            float e0 = v0 + adv, e1 = v1 + adv, e2 = v2 + adv, e3 = v3 + adv;
            e0 = fmaxf(e0, 0.2f * e0); e1 = fmaxf(e1, 0.2f * e1);
            e2 = fmaxf(e2, 0.2f * e2); e3 = fmaxf(e3, 0.2f * e3);
            e0 = fminf(e0, 80.f); e1 = fminf(e1, 80.f);
            e2 = fminf(e2, 80.f); e3 = fminf(e3, 80.f);
            float x0 = __expf(e0), x1 = __expf(e1), x2 = __expf(e2), x3 = __expf(e3);
            union { unsigned int u; float f; } cl0, ch0, cl1, ch1, cl2, ch2, cl3, ch3;
            cl0.u = q0 << 16; ch0.u = q0 & 0xFFFF0000u;
            cl1.u = q1 << 16; ch1.u = q1 & 0xFFFF0000u;
            cl2.u = q2 << 16; ch2.u = q2 & 0xFFFF0000u;
            cl3.u = q3 << 16; ch3.u = q3 & 0xFFFF0000u;
            den += x0; den += x1; den += x2; den += x3;
            a0 = fmaf(x0, cl0.f, a0); a0 = fmaf(x1, cl1.f, a0);
            a0 = fmaf(x2, cl2.f, a0); a0 = fmaf(x3, cl3.f, a0);
            a1 = fmaf(x0, ch0.f, a1); a1 = fmaf(x1, ch1.f, a1);
            a1 = fmaf(x2, ch2.f, a1); a1 = fmaf(x3, ch3.f, a1);
        }
        for (; j < nb; ++j) {
            int s0 = __shfl(myidx, j, 64);
            float v0 = asrc[s0 * NHEAD + head];
            unsigned int q0 = *(const unsigned int*)(Hl + (size_t)s0 * HID);
            float e0 = v0 + adv;
            e0 = fmaxf(e0, 0.2f * e0);
            e0 = fminf(e0, 80.f);
            float x0 = __expf(e0);
            union { unsigned int u; float f; } cl0, ch0;
            cl0.u = q0 << 16; ch0.u = q0 & 0xFFFF0000u;
            den += x0;
            a0 = fmaf(x0, cl0.f, a0);
            a1 = fmaf(x0, ch0.f, a1);
        }
    }
    float inv = 1.f / (den + 1e-16f);
    unsigned int lo16 = (unsigned short)f2s(fmaxf(a0 * inv, 0.f));
    unsigned int hi16 = (unsigned short)f2s(fmaxf(a1 * inv, 0.f));
    *(unsigned int*)(outb + (size_t)dn * HID + lane * 2) = lo16 | (hi16 << 16);
}

// ---------------- semantic score via MFMA (+fused beta in last block) ----------------
__global__ __launch_bounds__(256) void score_mfma(
    const short* __restrict__ out_nn, const short* __restrict__ out_in,
    const short* __restrict__ wkT, const short* __restrict__ cp,
    float* __restrict__ Ssum, int* __restrict__ done_cnt,
    float* __restrict__ beta, int total_blocks)
{
    __shared__ float col_s[HID];
    __shared__ int lastflag;
    int tid  = threadIdx.x;
    int lane = tid & 63;
    int wid  = tid >> 6;
    int quad = lane >> 4;
    int lm   = lane & 15;
    const short* src = blockIdx.y ? out_in : out_nn;
    int m0 = blockIdx.x * 128;

    if (tid < HID) col_s[tid] = 0.f;
    __syncthreads();

    float4_t acc[2][8];
    #pragma unroll
    for (int i = 0; i < 2; ++i)
        #pragma unroll
        for (int c = 0; c < 8; ++c)
            acc[i][c] = (float4_t){0.f, 0.f, 0.f, 0.f};

    #pragma unroll
    for (int kc = 0; kc < 4; ++kc) {
        short8_t bfrag[8];
        #pragma unroll
        for (int c = 0; c < 8; ++c)
            bfrag[c] = *(const short8_t*)(wkT + (c * 16 + lm) * HID + kc * 32 + quad * 8);
        #pragma unroll
        for (int i = 0; i < 2; ++i) {
            int gm = m0 + wid * 32 + i * 16 + lm;
            if (gm >= N_NODES) gm = N_NODES - 1;
            short8_t afrag = *(const short8_t*)(src + (size_t)gm * HID + kc * 32 + quad * 8);
            #pragma unroll
            for (int c = 0; c < 8; ++c)
                acc[i][c] = __builtin_amdgcn_mfma_f32_16x16x32_bf16(afrag, bfrag[c], acc[i][c], 0, 0, 0);
        }
    }

    #pragma unroll
    for (int c = 0; c < 8; ++c) {
        int col = c * 16 + lm;
        float bkc = b2f(cp[CP_BK + col]);
        float lsum = 0.f;
        #pragma unroll
        for (int i = 0; i < 2; ++i)
            #pragma unroll
            for (int r = 0; r < 4; ++r) {
                int node = m0 + wid * 32 + i * 16 + quad * 4 + r;
                if (node < N_NODES) {
                    float a = acc[i][c][r] + bkc;
                    a = fminf(fmaxf(a, -15.f), 15.f);
                    float t = __expf(2.f * a);
                    lsum += (t - 1.f) / (t + 1.f);
                }
            }
        float v = lsum;
        v += __shfl_down(v, 32, 64);
        v += __shfl_down(v, 16, 64);
        if (quad == 0) atomicAdd(&col_s[col], v);
    }
    __syncthreads();
    if (tid < HID) atomicAdd(&Ssum[blockIdx.y * HID + tid], col_s[tid]);
    __syncthreads();

    if (tid == 0) {
        __threadfence();
        int old = atomicAdd(done_cnt, 1);
        lastflag = (old == total_blocks - 1) ? 1 : 0;
    }
    __syncthreads();
    if (lastflag && tid < 64) {
        float s00 = atomicAdd(&Ssum[tid], 0.f);
        float s01 = atomicAdd(&Ssum[tid + 64], 0.f);
        float s10 = atomicAdd(&Ssum[128 + tid], 0.f);
        float s11 = atomicAdd(&Ssum[192 + tid], 0.f);
        float q0 = b2f(cp[CP_Q + tid]), q1 = b2f(cp[CP_Q + tid + 64]);
        float v0 = q0 * s00 + q1 * s01;
        float v1 = q0 * s10 + q1 * s11;
        #pragma unroll
        for (int off = 32; off; off >>= 1) {
            v0 += __shfl_down(v0, off, 64);
            v1 += __shfl_down(v1, off, 64);
        }
        if (tid == 0) {
            float sc0 = v0 / (float)N_NODES;
            float sc1 = v1 / (float)N_NODES;
            float mx = fmaxf(sc0, sc1);
            float e0 = __expf(sc0 - mx), e1 = __expf(sc1 - mx);
            float inv = 1.f / (e0 + e1);
            beta[0] = e0 * inv;
            beta[1] = e1 * inv;
        }
    }
}

// ---------------- final ----------------
__global__ __launch_bounds__(256) void final_out(
    const short* __restrict__ out_nn, const short* __restrict__ out_in,
    const float* __restrict__ beta, const short* __restrict__ cp,
    void* __restrict__ Yraw, const int* __restrict__ flag)
{
    bool isbf = (*flag != 0);
    int tid = threadIdx.x, lane = tid & 63, w = tid >> 6;
    int n = blockIdx.x * 4 + w;
    float b0 = beta[0], b1 = beta[1];
    unsigned int u0 = *(const unsigned int*)(out_nn + (size_t)n * HID + lane * 2);
    unsigned int u1 = *(const unsigned int*)(out_in + (size_t)n * HID + lane * 2);
    union { unsigned int u; float f; } t;
    t.u = u0 << 16;          float f0 = b0 * t.f;
    t.u = u0 & 0xFFFF0000u;  float f1 = b0 * t.f;
    t.u = u1 << 16;          f0 += b1 * t.f;
    t.u = u1 & 0xFFFF0000u;  f1 += b1 * t.f;
    float e0 = (f0 > 0.f) ? f0 : expm1f(f0);
    float e1 = (f1 > 0.f) ? f1 : expm1f(f1);
    int c0 = lane * 2, c1 = lane * 2 + 1;
    float p[C_OUT];
    #pragma unroll
    for (int c = 0; c < C_OUT; ++c)
        p[c] = e0 * b2f(cp[CP_WOUT + c0 * C_OUT + c]) + e1 * b2f(cp[CP_WOUT + c1 * C_OUT + c]);
    #pragma unroll
    for (int off = 32; off; off >>= 1)
        #pragma unroll
        for (int c = 0; c < C_OUT; ++c) p[c] += __shfl_down(p[c], off, 64);
    if (lane == 0) {
        #pragma unroll
        for (int c = 0; c < C_OUT; ++c) {
            float r = p[c] + b2f(cp[CP_BOUT + c]);
            if (isbf) ((__hip_bfloat16*)Yraw)[n * C_OUT + c] = __float2bfloat16(r);
            else      ((float*)Yraw)[n * C_OUT + c] = r;
        }
    }
}

// ---------------- launch ----------------
extern "C" void kernel_launch(void* const* d_in, const int* in_sizes, int n_in,
                              void* d_out, int out_size, void* d_ws, size_t ws_size,
                              hipStream_t stream) {
    const void* x_news  = d_in[0];
    const void* x_inter = d_in[1];
    const int*  edge_nn = (const int*)d_in[2];
    const int*  edge_in = (const int*)d_in[3];

    int E_nn = in_sizes[2] / 2;
    int E_in = in_sizes[3] / 2;

    char* ws = (char*)d_ws;
    short* h_news  = (short*)(ws + OFF_H_NEWS);
    short* h_inter = (short*)(ws + OFF_H_INTER);
    short* out_nn  = (short*)(ws + OFF_OUT_NN);
    short* out_in  = (short*)(ws + OFF_OUT_IN);
    float* asrc_nn = (float*)(ws + OFF_ASRC_NN);
    float* adst_nn = (float*)(ws + OFF_ADST_NN);
    float* asrc_in = (float*)(ws + OFF_ASRC_IN);
    float* adst_in = (float*)(ws + OFF_ADST_IN);
    short* wt_news  = (short*)(ws + OFF_WT_NEWS);
    short* wt_inter = (short*)(ws + OFF_WT_INTER);
    int* rs_nn   = (int*)(ws + OFF_RS_NN);
    int* rs_in   = (int*)(ws + OFF_RS_IN);
    int* sort_nn = (int*)(ws + OFF_SORT_NN);
    int* sort_in = (int*)(ws + OFF_SORT_IN);
    int* deg_nn  = (int*)(ws + OFF_DEG_NN);
    int* fill_nn = (int*)(ws + OFF_FILL_NN);
    int* deg_in  = (int*)(ws + OFF_DEG_IN);
    int* fill_in = (int*)(ws + OFF_FILL_IN);
    float* Ssum  = (float*)(ws + OFF_SSUM);
    int*   dcnt  = (int*)(ws + OFF_CNT);
    float* beta  = (float*)(ws + OFF_BETA);
    int*   flag  = (int*)(ws + OFF_FLAG);
    short* cp    = (short*)(ws + OFF_CPAR);
    short* wkT   = (short*)(ws + OFF_WKT);

    SmallParams sp;
    const int srcidx[10] = {5, 7, 8, 9, 10, 11, 13, 14, 15, 16};
    const int ns[10]     = {128, 128, 128, 128, 128, 128, 128, 128, 512, 4};
    const int doff[10]   = {CP_B_NEWS, CP_B_INTER, CP_ASRC_NN, CP_ADST_NN, CP_ASRC_IN,
                            CP_ADST_IN, CP_BK, CP_Q, CP_WOUT, CP_BOUT};
    for (int i = 0; i < 10; ++i) { sp.src[i] = d_in[srcidx[i]]; sp.n[i] = ns[i]; sp.dstoff[i] = doff[i]; }

    prep<<<PREP_TOTAL, 256, 0, stream>>>(sp, cp, d_in[4], d_in[6], d_in[12],
                                         wt_news, wt_inter, wkT, ws + OFF_ZERO,
                                         (const unsigned int*)x_news, flag);

    int cntB = (E_nn + E_in + 255) / 256;
    proj_count<<<cntB + 2 * GEMM_BX, 256, 0, stream>>>(
        x_news, x_inter, wt_news, wt_inter, cp, h_news, h_inter,
        asrc_nn, adst_nn, asrc_in, adst_in,
        edge_nn + E_nn, E_nn, edge_in + E_in, E_in,
        deg_nn, deg_in, rs_nn, rs_in,
        cntB, dcnt + 1,
        N_NODES, flag);

    scatter_edges2<<<cntB, 256, 0, stream>>>(
        edge_nn, E_nn, edge_in, E_in, rs_nn, fill_nn, sort_nn, rs_in, fill_in, sort_in);

    aggregate2<<<dim3(N_NODES / 4, 2), 256, 0, stream>>>(
        h_news, h_inter, asrc_nn, adst_nn, asrc_in, adst_in,
        rs_nn, rs_in, sort_nn, sort_in, out_nn, out_in);

    int score_bx = (N_NODES + 127) / 128;
    score_mfma<<<dim3(score_bx, 2), 256, 0, stream>>>(
        out_nn, out_in, wkT, cp, Ssum, dcnt, beta, 2 * score_bx);

    final_out<<<N_NODES / 4, 256, 0, stream>>>(out_nn, out_in, beta, cp, d_out, flag);
}